// Round 5
// baseline (58.792 us; speedup 1.0000x reference)
//
#include <hip/hip_runtime.h>
#include <hip/hip_bf16.h>

// ZDecoder: qs[b,c,o] = MLP(concat(V(c), phi(b)))
// Layer-1 separability: h1[b,c] = relu(A[c] + P[b]),
//   A[c] = sum_l Bt[l][(c>>3l)&7],  P[b][h] = b1[h] + w1[:,64:]*phi[b]
// R4 post-mortem: store shape irrelevant (fills prove no write-allocate);
// bound = 2 waves/SIMD occupancy + serial LDS-transpose chain.
// R5: layer-2 operand swap (A=w2,B=h1) -> D2[m=g][n=combo]; lane's D2 regs
// ARE the K=16 B-fragment -> layer 3 via 8x mfma_f32_16x16x16_bf16 straight
// from registers. No LDS writes / lgkmcnt waits in main loop. Register diet
// + launch_bounds(256,4) -> 4 waves/SIMD, grid 1024 = 4 blocks/CU, 1 round.

typedef __attribute__((ext_vector_type(8))) short bf16x8;
typedef __attribute__((ext_vector_type(4))) short bf16x4;
typedef __attribute__((ext_vector_type(4))) float f32x4;

#define MFMA_K32(a, b, c) __builtin_amdgcn_mfma_f32_16x16x32_bf16(a, b, c, 0, 0, 0)

#if defined(__has_builtin)
#if __has_builtin(__builtin_amdgcn_mfma_f32_16x16x16bf16_1k)
#define MFMA_K16(a, b, c) __builtin_amdgcn_mfma_f32_16x16x16bf16_1k(a, b, c, 0, 0, 0)
#elif __has_builtin(__builtin_amdgcn_mfma_f32_16x16x16_bf16)
#define MFMA_K16(a, b, c) __builtin_amdgcn_mfma_f32_16x16x16_bf16(a, b, c, 0, 0, 0)
#endif
#endif
#ifndef MFMA_K16
__device__ __forceinline__ f32x4 mfma_k16_asm(bf16x4 a, bf16x4 b, f32x4 c) {
    f32x4 d;
    asm("v_mfma_f32_16x16x16_bf16 %0, %1, %2, %3" : "=v"(d) : "v"(a), "v"(b), "v"(c));
    return d;
}
#define MFMA_K16(a, b, c) mfma_k16_asm(a, b, c)
#endif

__device__ __forceinline__ short f2bf(float x) {
    union { __hip_bfloat16 b; short s; } u;
    u.b = __float2bfloat16(x);
    return u.s;
}

__device__ __forceinline__ float4 ldg4(const float* p) {
    return *reinterpret_cast<const float4*>(p);
}

__global__ __launch_bounds__(256, 4)
void zdec_kernel(const float* __restrict__ phi, const float* __restrict__ rp,
                 const float* __restrict__ w1, const float* __restrict__ b1,
                 const float* __restrict__ w2, const float* __restrict__ b2,
                 const float* __restrict__ w3, const float* __restrict__ b3,
                 float* __restrict__ out)
{
    // 28 KiB: At[4096] | Pt[1024] | Bt[2048]  (no main-loop LDS writes)
    __shared__ float smem[7168];
    float* const At = smem;          // [64 combos][64 h], XOR-swizzled
    float* const Pt = smem + 4096;   // [16 batches][64 h], linear
    float* const Bt = smem + 5120;   // setup: [4 lv][8 rg][64 h]

    const int t  = threadIdx.x;
    const int cb = blockIdx.x & 63;   // combo tile: 64 tiles of 64 combos
    const int bb = blockIdx.x >> 6;   // batch tile: 16 tiles of 16 batches
    const int c0 = cb << 6;
    const int b0 = bb << 4;

    // ---------------- setup: B table ----------------
    {
        const int l = t >> 6, h = t & 63;
        float ws[16];
#pragma unroll
        for (int z4 = 0; z4 < 4; ++z4) {
            const float4 v = ldg4(w1 + h * 128 + l * 16 + z4 * 4);
            ws[z4*4+0] = v.x; ws[z4*4+1] = v.y; ws[z4*4+2] = v.z; ws[z4*4+3] = v.w;
        }
#pragma unroll
        for (int r = 0; r < 8; ++r) {
            float acc = 0.f;
#pragma unroll
            for (int z4 = 0; z4 < 4; ++z4) {
                const float4 v = ldg4(rp + (l * 8 + r) * 16 + z4 * 4);
                acc += ws[z4*4+0]*v.x + ws[z4*4+1]*v.y + ws[z4*4+2]*v.z + ws[z4*4+3]*v.w;
            }
            Bt[(l * 8 + r) * 64 + h] = acc;
        }
    }
    // ---------------- setup: P rows ----------------
    {
        const int h = t & 63, bg = t >> 6;
        const float bias = b1[h];
        float acc[4] = {bias, bias, bias, bias};
#pragma unroll
        for (int p4 = 0; p4 < 16; ++p4) {
            const float4 wvv = ldg4(w1 + h * 128 + 64 + p4 * 4);
#pragma unroll
            for (int bj = 0; bj < 4; ++bj) {
                const float4 pv = ldg4(phi + (b0 + bg * 4 + bj) * 64 + p4 * 4);
                acc[bj] += wvv.x * pv.x + wvv.y * pv.y + wvv.z * pv.z + wvv.w * pv.w;
            }
        }
#pragma unroll
        for (int bj = 0; bj < 4; ++bj)
            Pt[(bg * 4 + bj) * 64 + h] = acc[bj];
    }
    __syncthreads();
    // ---------------- setup: A tile (swizzled; reads Bt, writes At) ----------------
    {
        const int h = t & 63, cg = t >> 6;
        const int r2 = (c0 >> 6) & 7, r3 = (c0 >> 9) & 7;  // uniform over 64-combo tile
        const float c23 = Bt[(16 + r2) * 64 + h] + Bt[(24 + r3) * 64 + h];
#pragma unroll
        for (int cc = 0; cc < 16; ++cc) {
            const int ct = cg * 16 + cc;
            const float v = c23 + Bt[(ct & 7) * 64 + h] + Bt[(8 + ((ct >> 3) & 7)) * 64 + h];
            At[ct * 64 + (h ^ ((ct & 15) << 2))] = v;
        }
    }
    __syncthreads();

    // ---------------- main: per-wave 16 combos x 16 batches ----------------
    const int lane = t & 63;
    const int wid  = t >> 6;
    const int q = lane >> 4;         // quarter-wave group
    const int s = lane & 15;
    const int mct = (wid << 4) + s;  // this lane's combo row

    // w2 as layer-2 A-operand: A[m=g-row=s+16nt][k=h=kt*32+q*8+j]  (32 VGPR)
    bf16x8 w2f[4][2];
#pragma unroll
    for (int nt = 0; nt < 4; ++nt)
#pragma unroll
        for (int kt = 0; kt < 2; ++kt) {
            const float* src = w2 + (nt * 16 + s) * 64 + kt * 32 + q * 8;
            const float4 v0 = ldg4(src), v1 = ldg4(src + 4);
            bf16x8 f;
            f[0]=f2bf(v0.x); f[1]=f2bf(v0.y); f[2]=f2bf(v0.z); f[3]=f2bf(v0.w);
            f[4]=f2bf(v1.x); f[5]=f2bf(v1.y); f[6]=f2bf(v1.z); f[7]=f2bf(v1.w);
            w2f[nt][kt] = f;
        }
    // w3 as layer-3 K=16 A-operand: A[m=o=s+16nt3][k=g=nt*16+q*4+j]  (16 VGPR)
    bf16x4 w3f[2][4];
#pragma unroll
    for (int nt3 = 0; nt3 < 2; ++nt3)
#pragma unroll
        for (int nt = 0; nt < 4; ++nt) {
            const float4 v = ldg4(w3 + (nt3 * 16 + s) * 64 + nt * 16 + q * 4);
            bf16x4 f;
            f[0]=f2bf(v.x); f[1]=f2bf(v.y); f[2]=f2bf(v.z); f[3]=f2bf(v.w);
            w3f[nt3][nt] = f;
        }
    // biases as acc-init vectors: D2 reg r -> g=nt*16+q*4+r; D3 reg r -> o=nt3*16+q*4+r
    f32x4 b2i[4];
#pragma unroll
    for (int nt = 0; nt < 4; ++nt) {
        const float4 v = ldg4(b2 + nt * 16 + q * 4);
        b2i[nt] = f32x4{v.x, v.y, v.z, v.w};
    }
    f32x4 b3i[2];
#pragma unroll
    for (int nt3 = 0; nt3 < 2; ++nt3) {
        const float4 v = ldg4(b3 + nt3 * 16 + q * 4);
        b3i[nt3] = f32x4{v.x, v.y, v.z, v.w};
    }

    const int amask = s << 2;  // mct&15 == s
    // store base: combo = c0+wid*16+s, o = nt3*16 + q*4 + r (f32x4 over r)
    float* gwave = out + (size_t)(b0 * 4096 + c0 + (wid << 4) + s) * 32 + q * 4;

    for (int bi = 0; bi < 16; ++bi) {
        // h1 fragment (B-operand): [n=combo=s][k=h=q*8+j (+32)]
        bf16x8 h1f0, h1f1;
#pragma unroll
        for (int half = 0; half < 2; ++half) {
            float tmp[8];
#pragma unroll
            for (int ch = 0; ch < 2; ++ch) {
                const int hc = half * 32 + q * 8 + ch * 4;
                const f32x4 av = *reinterpret_cast<const f32x4*>(At + mct * 64 + (hc ^ amask));
                const f32x4 pv = *reinterpret_cast<const f32x4*>(Pt + bi * 64 + hc);
#pragma unroll
                for (int j = 0; j < 4; ++j) tmp[ch*4+j] = fmaxf(av[j] + pv[j], 0.f);
            }
            bf16x8& dst = half ? h1f1 : h1f0;
#pragma unroll
            for (int j = 0; j < 8; ++j) dst[j] = f2bf(tmp[j]);
        }

        // layer 2: D2[m=g][n=combo], bias via acc-init
        f32x4 a2[4];
#pragma unroll
        for (int nt = 0; nt < 4; ++nt) {
            f32x4 acc = b2i[nt];
            acc = MFMA_K32(w2f[nt][0], h1f0, acc);
            acc = MFMA_K32(w2f[nt][1], h1f1, acc);
            a2[nt] = acc;
        }
        // relu + cvt: lane's D2 regs are exactly the K=16 B-fragment [n=s][k=g=q*4+r]
        bf16x4 h2f[4];
#pragma unroll
        for (int nt = 0; nt < 4; ++nt) {
            bf16x4 f;
#pragma unroll
            for (int r = 0; r < 4; ++r) f[r] = f2bf(fmaxf(a2[nt][r], 0.f));
            h2f[nt] = f;
        }
        // layer 3: D3[m=o][n=combo] via 8x K=16 MFMA, direct f32x4 stores
        float* gb = gwave + (size_t)bi * 131072;  // (b0+bi)*4096*32
#pragma unroll
        for (int nt3 = 0; nt3 < 2; ++nt3) {
            f32x4 acc = b3i[nt3];
#pragma unroll
            for (int nt = 0; nt < 4; ++nt)
                acc = MFMA_K16(w3f[nt3][nt], h2f[nt], acc);
            __builtin_nontemporal_store(acc, reinterpret_cast<f32x4*>(gb + nt3 * 16));
        }
    }
}

extern "C" void kernel_launch(void* const* d_in, const int* in_sizes, int n_in,
                              void* d_out, int out_size, void* d_ws, size_t ws_size,
                              hipStream_t stream) {
    const float* phi = (const float*)d_in[0];
    const float* rp  = (const float*)d_in[1];
    const float* w1  = (const float*)d_in[2];
    const float* b1  = (const float*)d_in[3];
    const float* w2  = (const float*)d_in[4];
    const float* b2  = (const float*)d_in[5];
    const float* w3  = (const float*)d_in[6];
    const float* b3  = (const float*)d_in[7];
    (void)in_sizes; (void)n_in; (void)out_size; (void)d_ws; (void)ws_size;

    zdec_kernel<<<dim3(1024), dim3(256), 0, stream>>>(
        phi, rp, w1, b1, w2, b2, w3, b3, (float*)d_out);
}